// Round 5
// baseline (21.352 us; speedup 1.0000x reference)
//
#include <hip/hip_runtime.h>

// Problem constants (from reference): B=128, TX=400, ENC=512, DEC=512.
// Key insight: jax.nn.softmax over a size-1 axis => alpha == 1 everywhere.
//   Output 0: context[b, e] = sum_tx a[b, tx, e]          (B*ENC  = 65536 floats)
//   Output 1: alpha[b, tx]  = 1.0f                        (B*TX   = 51200 floats)
// Everything else in the reference (Wmat, tanh, coverage, v, w, b) is dead code.
//
// Single fused kernel, no atomics:
//   grid = B * ECHUNKS = 512 blocks; block (b, ec) exclusively owns
//   context[b, ec*128:(ec+1)*128] -> plain stores, no zero-init needed.
//   512 threads = 16 tx-groups x 32 float4-lanes (4 waves/SIMD at 2 blocks/CU
//   for latency hiding); LDS tree-reduce over groups.
//   NOTE: plain (cacheable) loads on purpose — `a` (105 MB) fits in the
//   256 MB Infinity Cache and is re-read on every graph replay; the
//   nontemporal hint would discourage MALL retention.
//   Each block also writes its private 100-float slice of alpha (25 x float4).

#define BB      128
#define TXX     400
#define ENCC    512
#define ECHUNKS 4
#define ECW     (ENCC / ECHUNKS)   // 128 floats per chunk
#define ECV     (ECW / 4)          // 32 float4 per chunk
#define GROUPS  16
#define TPB     (GROUPS * ECV)     // 512 threads
#define TX_PER  (TXX / GROUPS)     // 25 rows per group
#define ALPHA_PER 100              // (BB*TXX)/(BB*ECHUNKS) floats per block

typedef float f32x4 __attribute__((ext_vector_type(4)));

__global__ __launch_bounds__(TPB) void bahdanau_fused_kernel(
        const float* __restrict__ a, float* __restrict__ out) {
    const int blk = blockIdx.x;
    const int b   = blk >> 2;          // / ECHUNKS
    const int ec  = blk & (ECHUNKS - 1);
    const int g   = threadIdx.x >> 5;  // tx group 0..15
    const int l   = threadIdx.x & 31;  // float4 lane within chunk

    // a viewed as f32x4: row stride = ENCC/4 = 128
    const f32x4* base = reinterpret_cast<const f32x4*>(a)
                      + (size_t)b * (TXX * (ENCC / 4))
                      + ec * ECV + l;

    f32x4 acc = (f32x4)(0.f);
    #pragma unroll
    for (int k = 0; k < TX_PER; ++k) {
        acc += base[(size_t)(g + k * GROUPS) * (ENCC / 4)];
    }

    __shared__ f32x4 lds[TPB];
    lds[threadIdx.x] = acc;
    __syncthreads();

    // tree-reduce the 16 group-partials down to group 0
    #pragma unroll
    for (int s = TPB / 2; s >= ECV; s >>= 1) {
        if (threadIdx.x < s) {
            lds[threadIdx.x] += lds[threadIdx.x + s];
        }
        __syncthreads();
    }

    if (threadIdx.x < ECV) {
        reinterpret_cast<f32x4*>(out + (size_t)b * ENCC + ec * ECW)[threadIdx.x]
            = lds[threadIdx.x];
    }

    // alpha = 1.0f; each block writes a private 100-float (25 f32x4) slice
    f32x4* alpha4 = reinterpret_cast<f32x4*>(out + BB * ENCC
                                             + (size_t)blk * ALPHA_PER);
    if (threadIdx.x < ALPHA_PER / 4) {
        alpha4[threadIdx.x] = (f32x4)(1.f);
    }
}

extern "C" void kernel_launch(void* const* d_in, const int* in_sizes, int n_in,
                              void* d_out, int out_size, void* d_ws, size_t ws_size,
                              hipStream_t stream) {
    const float* a = (const float*)d_in[0];   // (B, TX, ENC) float32
    float* out = (float*)d_out;               // [context (B*ENC) | alpha (B*TX)]

    bahdanau_fused_kernel<<<BB * ECHUNKS, TPB, 0, stream>>>(a, out);
}

// Round 6
// 19.036 us; speedup vs baseline: 1.1217x; 1.1217x over previous
//
#include <hip/hip_runtime.h>

// Problem constants (from reference): B=128, TX=400, ENC=512, DEC=512.
// Key insight: jax.nn.softmax over a size-1 axis => alpha == 1 everywhere.
//   Output 0: context[b, e] = sum_tx a[b, tx, e]          (B*ENC  = 65536 floats)
//   Output 1: alpha[b, tx]  = 1.0f                        (B*TX   = 51200 floats)
// Everything else in the reference (Wmat, tanh, coverage, v, w, b) is dead code.
//
// Single fused kernel, no atomics:
//   grid = B * ECHUNKS = 512 blocks; block (b, ec) exclusively owns
//   context[b, ec*128:(ec+1)*128] -> plain stores, no zero-init needed.
//   512 threads = 16 tx-groups x 32 float4-lanes (4 waves/SIMD at 2 blocks/CU).
//   A/B (r4 vs r5) proved nontemporal loads are +11% vs cacheable: keep nt.
//   Tail trims: alpha stores issued before the barrier (overlap reduce);
//   wave-level shfl_xor(32) pre-reduce collapses 16 partials -> 8 in-register,
//   LDS tree is then 3 rounds instead of 4.

#define BB      128
#define TXX     400
#define ENCC    512
#define ECHUNKS 4
#define ECW     (ENCC / ECHUNKS)   // 128 floats per chunk
#define ECV     (ECW / 4)          // 32 float4 per chunk
#define GROUPS  16
#define TPB     (GROUPS * ECV)     // 512 threads
#define TX_PER  (TXX / GROUPS)     // 25 rows per group
#define ALPHA_PER 100              // (BB*TXX)/(BB*ECHUNKS) floats per block

typedef float f32x4 __attribute__((ext_vector_type(4)));

__global__ __launch_bounds__(TPB) void bahdanau_fused_kernel(
        const float* __restrict__ a, float* __restrict__ out) {
    const int blk = blockIdx.x;
    const int b   = blk >> 2;          // / ECHUNKS
    const int ec  = blk & (ECHUNKS - 1);
    const int g   = threadIdx.x >> 5;  // tx group 0..15
    const int l   = threadIdx.x & 31;  // float4 lane within chunk

    // a viewed as f32x4: row stride = ENCC/4 = 128
    const f32x4* base = reinterpret_cast<const f32x4*>(a)
                      + (size_t)b * (TXX * (ENCC / 4))
                      + ec * ECV + l;

    f32x4 acc = (f32x4)(0.f);
    #pragma unroll
    for (int k = 0; k < TX_PER; ++k) {
        acc += __builtin_nontemporal_load(
            &base[(size_t)(g + k * GROUPS) * (ENCC / 4)]);
    }

    // alpha = 1.0f; issue before the barrier so the store latency overlaps
    // the LDS reduce. Each block owns a private 100-float (25 f32x4) slice.
    f32x4* alpha4 = reinterpret_cast<f32x4*>(out + BB * ENCC
                                             + (size_t)blk * ALPHA_PER);
    if (threadIdx.x < ALPHA_PER / 4) {
        alpha4[threadIdx.x] = (f32x4)(1.f);
    }

    // wave-level pre-reduce: thread = g*32 + l, so one wave = two tx-groups.
    // shfl_xor across the 32-lane half combines group pairs in-register.
    {
        f32x4 o;
        o.x = __shfl_xor(acc.x, 32, 64);
        o.y = __shfl_xor(acc.y, 32, 64);
        o.z = __shfl_xor(acc.z, 32, 64);
        o.w = __shfl_xor(acc.w, 32, 64);
        acc += o;
    }

    __shared__ f32x4 lds[TPB / 2];     // 8 group-pairs x 32 lanes
    const int wid  = threadIdx.x >> 6; // wave 0..7 (= group pair)
    const int lane = threadIdx.x & 63;
    if (lane < 32) {
        lds[wid * 32 + lane] = acc;
    }
    __syncthreads();

    // tree-reduce 8 group-pair partials down to 1 (3 rounds)
    #pragma unroll
    for (int s = 128; s >= ECV; s >>= 1) {
        if (threadIdx.x < s) {
            lds[threadIdx.x] += lds[threadIdx.x + s];
        }
        __syncthreads();
    }

    if (threadIdx.x < ECV) {
        reinterpret_cast<f32x4*>(out + (size_t)b * ENCC + ec * ECW)[threadIdx.x]
            = lds[threadIdx.x];
    }
}

extern "C" void kernel_launch(void* const* d_in, const int* in_sizes, int n_in,
                              void* d_out, int out_size, void* d_ws, size_t ws_size,
                              hipStream_t stream) {
    const float* a = (const float*)d_in[0];   // (B, TX, ENC) float32
    float* out = (float*)d_out;               // [context (B*ENC) | alpha (B*TX)]

    bahdanau_fused_kernel<<<BB * ECHUNKS, TPB, 0, stream>>>(a, out);
}